// Round 11
// baseline (206.736 us; speedup 1.0000x reference)
//
#include <hip/hip_runtime.h>
#include <hip/hip_fp16.h>

#define NN 100000
#define NE 1600000
#define NPAD 100352          // NN rounded up to 256
#define ST 68                // LDS t-tile stride (16B-aligned rows, conflict-checked)
#define SXS 68               // gemm1 sX stride: 68%32=4 -> r0-groups hit distinct banks
#define NB 256               // hist/scatter blocks (NE % NB == 0 -> 6250 edges each)
#define CE (NE / NB)
#define D1 391               // dst>>8 buckets (99999>>8 = 390)
#define L1 (D1 * NB)         // flattened hist size = 100096

// ================= CSR build: bucket sort, ZERO scattered global atomics ======

// per-block LDS histogram of dst>>8 -> H[d*NB + b]
__global__ __launch_bounds__(256) void k_hist(const int* __restrict__ dst,
                                              unsigned* __restrict__ H) {
    __shared__ unsigned h[D1];
    int b = blockIdx.x, t = threadIdx.x;
    for (int i = t; i < D1; i += 256) h[i] = 0;
    __syncthreads();
    int beg = b * CE, end = beg + CE;
    for (int i = beg + t; i < end; i += 256)
        atomicAdd(&h[((unsigned)dst[i]) >> 8], 1u);
    __syncthreads();
    for (int d = t; d < D1; d += 256) H[d * NB + b] = h[d];
}

__global__ __launch_bounds__(256) void k_scanA(const unsigned* __restrict__ in,
                                               unsigned* __restrict__ bsum, int L) {
    __shared__ unsigned sp[256];
    int i = blockIdx.x * 256 + threadIdx.x;
    sp[threadIdx.x] = (i < L) ? in[i] : 0;
    __syncthreads();
    for (int off = 128; off > 0; off >>= 1) {
        if (threadIdx.x < off) sp[threadIdx.x] += sp[threadIdx.x + off];
        __syncthreads();
    }
    if (threadIdx.x == 0) bsum[blockIdx.x] = sp[0];
}

__global__ __launch_bounds__(512) void k_scanB(unsigned* __restrict__ bsum, int nb) {
    __shared__ unsigned sp[512];
    int t = threadIdx.x;
    unsigned v = (t < nb) ? bsum[t] : 0;
    sp[t] = v;
    __syncthreads();
    for (int off = 1; off < 512; off <<= 1) {
        unsigned u = (t >= off) ? sp[t - off] : 0;
        __syncthreads();
        sp[t] += u;
        __syncthreads();
    }
    if (t < nb) bsum[t] = sp[t] - v;      // exclusive
}

__global__ __launch_bounds__(256) void k_scanC(unsigned* __restrict__ H,
                                               const unsigned* __restrict__ bsum, int L) {
    __shared__ unsigned sp[256];
    int t = threadIdx.x, i = blockIdx.x * 256 + t;
    unsigned v = (i < L) ? H[i] : 0;
    sp[t] = v;
    __syncthreads();
    for (int off = 1; off < 256; off <<= 1) {
        unsigned u = (t >= off) ? sp[t - off] : 0;
        __syncthreads();
        sp[t] += u;
        __syncthreads();
    }
    if (i < L) H[i] = bsum[blockIdx.x] + sp[t] - v;
}

// scatter edges into bucket-grouped order; LDS running counters only.
__global__ __launch_bounds__(256) void k_scat(const int* __restrict__ src,
                                              const int* __restrict__ dst,
                                              const unsigned* __restrict__ H,
                                              unsigned* __restrict__ pairs) {
    __shared__ unsigned base[D1];
    __shared__ unsigned run[D1];
    int b = blockIdx.x, t = threadIdx.x;
    for (int d = t; d < D1; d += 256) { base[d] = H[d * NB + b]; run[d] = 0; }
    __syncthreads();
    int beg = b * CE, end = beg + CE;
    for (int i = beg + t; i < end; i += 256) {
        unsigned dv = (unsigned)dst[i];
        unsigned d = dv >> 8;
        unsigned r = atomicAdd(&run[d], 1u);
        pairs[base[d] + r] = ((dv & 255u) << 24) | (unsigned)src[i];
    }
}

// per-bucket counting sort + degree-rank ordering.
// Emits rowptr, dinv, csr, and (order, begend): positions sorted by degree
// within each bucket so agg waves get equal-work node groups.
__global__ __launch_bounds__(256) void k_bucket(const unsigned* __restrict__ H,
                                                const unsigned* __restrict__ pairs,
                                                int* __restrict__ rowptr,
                                                float* __restrict__ dinv,
                                                int* __restrict__ csr,
                                                int* __restrict__ order,
                                                int2* __restrict__ begend) {
    __shared__ unsigned h[256], sc[256], run[256], key[256];
    int b = blockIdx.x, t = threadIdx.x;
    unsigned S = H[b * NB];
    unsigned Send = (b + 1 < D1) ? H[(b + 1) * NB] : NE;
    h[t] = 0; run[t] = 0;
    __syncthreads();
    for (unsigned i = S + t; i < Send; i += 256)
        atomicAdd(&h[pairs[i] >> 24], 1u);
    __syncthreads();
    unsigned v = h[t];
    sc[t] = v;
    __syncthreads();
    for (int off = 1; off < 256; off <<= 1) {
        unsigned u = (t >= off) ? sc[t - off] : 0;
        __syncthreads();
        sc[t] += u;
        __syncthreads();
    }
    unsigned ex = sc[t] - v;               // exclusive
    int node = (b << 8) + t;
    if (node < NN) {
        rowptr[node] = (int)(S + ex);
        dinv[node] = rsqrtf((float)v + 1.0f);   // +1 = self-loop
    }
    if (b == 0 && t == 0) rowptr[NN] = NE;
    sc[t] = ex;
    key[t] = (node < NN) ? ((v << 8) | (unsigned)t) : 0xFFFFFFFFu;  // invalid -> sort last
    __syncthreads();
    // csr placement (bucket-local window, L2-resident)
    for (unsigned i = S + t; i < Send; i += 256) {
        unsigned p = pairs[i];
        unsigned k = p >> 24;
        unsigned r = atomicAdd(&run[k], 1u);
        csr[S + sc[k] + r] = (int)(p & 0xFFFFFFu);
    }
    // bitonic sort key[] ascending (36 steps)
    for (int kk = 2; kk <= 256; kk <<= 1) {
        for (int jj = kk >> 1; jj > 0; jj >>= 1) {
            __syncthreads();
            int p = t ^ jj;
            if (p > t) {
                unsigned a = key[t], c = key[p];
                bool up = ((t & kk) == 0);
                if ((a > c) == up) { key[t] = c; key[p] = a; }
            }
        }
    }
    __syncthreads();
    unsigned kv = key[t];
    int nl2 = (int)(kv & 255u);
    int dg = (int)(kv >> 8);
    int pos = (b << 8) + t;
    order[pos] = (b << 8) + nl2;
    int bg = (int)(S + sc[nl2]);
    begend[pos] = make_int2(bg, bg + dg);
}

// ---------------- layer-1 GEMM: g1 = fp16( dinv .* (x @ W1) ) ----------------

__global__ __launch_bounds__(256, 4) void k_gemm1(const float* __restrict__ A,
                                                  const float* __restrict__ W,
                                                  const float* __restrict__ dinv,
                                                  __half* __restrict__ out, int n) {
    __shared__ float sX[32 * SXS];
    __shared__ float sW[64 * 64];
    int row0 = blockIdx.x * 32;
    for (int i = threadIdx.x; i < 16 * 64; i += 256)
        ((float4*)sW)[i] = ((const float4*)W)[i];
    for (int i = threadIdx.x; i < 32 * 16; i += 256) {
        int r = i >> 4, c4 = i & 15;
        int row = row0 + r;
        float4 v = (row < n) ? ((const float4*)(A + ((size_t)row << 6)))[c4]
                             : make_float4(0.f, 0.f, 0.f, 0.f);
        *(float4*)&sX[r * SXS + (c4 << 2)] = v;
    }
    __syncthreads();

    int ci = (threadIdx.x & 15) * 4;
    int r0 = (threadIdx.x >> 4) * 2;
    float acc[2][4] = {};
#pragma unroll 16
    for (int k = 0; k < 64; ++k) {
        float a0 = sX[r0 * SXS + k];
        float a1 = sX[(r0 + 1) * SXS + k];
        float4 w = *(const float4*)&sW[(k << 6) + ci];
        acc[0][0] += a0 * w.x; acc[0][1] += a0 * w.y;
        acc[0][2] += a0 * w.z; acc[0][3] += a0 * w.w;
        acc[1][0] += a1 * w.x; acc[1][1] += a1 * w.y;
        acc[1][2] += a1 * w.z; acc[1][3] += a1 * w.w;
    }
#pragma unroll
    for (int rr = 0; rr < 2; ++rr) {
        int row = row0 + r0 + rr;
        if (row < n) {
            float di = dinv[row];
            union { uint2 u; __half2 h[2]; } P;
            P.h[0] = __float22half2_rn(make_float2(acc[rr][0] * di, acc[rr][1] * di));
            P.h[1] = __float22half2_rn(make_float2(acc[rr][2] * di, acc[rr][3] * di));
            *(uint2*)(out + ((size_t)row << 6) + ci) = P.u;
        }
    }
}

// ---------------- aggregate: 32 ranked nodes/block, 8-lane group per node -------
// node = order[pos]; (beg,end) = begend[pos].  Degree-rank ordering makes the 8
// groups of a wave near-equal work. 8 gathers in flight per group.

#define ACC8(r) { \
    const __half2* hh_ = (const __half2*)&(r); \
    float2 f_; \
    f_ = __half22float2(hh_[0]); a[0].x += f_.x; a[0].y += f_.y; \
    f_ = __half22float2(hh_[1]); a[1].x += f_.x; a[1].y += f_.y; \
    f_ = __half22float2(hh_[2]); a[2].x += f_.x; a[2].y += f_.y; \
    f_ = __half22float2(hh_[3]); a[3].x += f_.x; a[3].y += f_.y; }

template <int MODE>
__global__ __launch_bounds__(256) void k_agg(const int* __restrict__ order,
                                             const int2* __restrict__ begend,
                                             const int* __restrict__ csr,
                                             const __half* __restrict__ g,
                                             const float* __restrict__ dinv,
                                             const float* __restrict__ bias,
                                             const float* __restrict__ Wn,
                                             const float* __restrict__ bias2,
                                             void* __restrict__ outv, int n) {
    constexpr int M = (MODE == 3) ? 40 : 64;
    __shared__ float sW[(MODE >= 2) ? 64 * M : 1];
    __shared__ float sT[(MODE >= 2) ? 32 * ST : 1];
    int tid = threadIdx.x;
    if (MODE >= 2) {
        for (int i = tid; i < 16 * M; i += 256)
            ((float4*)sW)[i] = ((const float4*)Wn)[i];
    }
    int n0 = blockIdx.x << 5;
    int lane = tid & 63, wid = tid >> 6;
    int ng = lane >> 3, fl = lane & 7;
    int nl = (wid << 3) + ng;              // block-local slot 0..31
    int pos = n0 + nl;
    bool valid = pos < n;                  // grid covers exactly n positions
    int node = 0, beg = 0, end = 0;
    if (valid) {
        node = order[pos];
        int2 be = begend[pos];
        beg = be.x; end = be.y;
    }
    const uint4* g4 = (const uint4*)g;     // one row = 8 uint4 (64 halves)

    float2 a[4] = {};
    int j = beg;
    for (; j + 8 <= end; j += 8) {         // 8 independent gathers in flight
        int s0 = csr[j],     s1 = csr[j + 1], s2 = csr[j + 2], s3 = csr[j + 3];
        int s4 = csr[j + 4], s5 = csr[j + 5], s6 = csr[j + 6], s7 = csr[j + 7];
        uint4 r0 = g4[((size_t)s0 << 3) + fl];
        uint4 r1 = g4[((size_t)s1 << 3) + fl];
        uint4 r2 = g4[((size_t)s2 << 3) + fl];
        uint4 r3 = g4[((size_t)s3 << 3) + fl];
        uint4 r4 = g4[((size_t)s4 << 3) + fl];
        uint4 r5 = g4[((size_t)s5 << 3) + fl];
        uint4 r6 = g4[((size_t)s6 << 3) + fl];
        uint4 r7 = g4[((size_t)s7 << 3) + fl];
        ACC8(r0); ACC8(r1); ACC8(r2); ACC8(r3);
        ACC8(r4); ACC8(r5); ACC8(r6); ACC8(r7);
    }
    if (j + 4 <= end) {
        int s0 = csr[j], s1 = csr[j + 1], s2 = csr[j + 2], s3 = csr[j + 3];
        uint4 r0 = g4[((size_t)s0 << 3) + fl];
        uint4 r1 = g4[((size_t)s1 << 3) + fl];
        uint4 r2 = g4[((size_t)s2 << 3) + fl];
        uint4 r3 = g4[((size_t)s3 << 3) + fl];
        ACC8(r0); ACC8(r1); ACC8(r2); ACC8(r3);
        j += 4;
    }
    for (; j < end; ++j) {
        int s = csr[j];
        uint4 r = g4[((size_t)s << 3) + fl];
        ACC8(r);
    }
    if (valid) {                           // self-loop
        uint4 r = g4[((size_t)node << 3) + fl];
        ACC8(r);
    }
    float di = valid ? dinv[node] : 0.f;
    float t[8] = { a[0].x, a[0].y, a[1].x, a[1].y, a[2].x, a[2].y, a[3].x, a[3].y };

    if (MODE == 1) {
        if (valid) {
            float4 b0 = *(const float4*)(bias + (fl << 3));
            float4 b1 = *(const float4*)(bias + (fl << 3) + 4);
            float bv[8] = { b0.x, b0.y, b0.z, b0.w, b1.x, b1.y, b1.z, b1.w };
            union { uint4 u; __half2 h[4]; } P;
#pragma unroll
            for (int k = 0; k < 4; ++k) {
                float o0 = fmaxf(t[2 * k]     * di + bv[2 * k],     0.f) * di;
                float o1 = fmaxf(t[2 * k + 1] * di + bv[2 * k + 1], 0.f) * di;
                P.h[k] = __float22half2_rn(make_float2(o0, o1));
            }
            ((uint4*)outv)[((size_t)node << 3) + fl] = P.u;
        }
        return;
    }

    // MODE 2/3: stash transformed row slice into sT
    {
        float4 b0 = make_float4(0.f, 0.f, 0.f, 0.f), b1 = b0;
        if (MODE == 2) {
            b0 = *(const float4*)(bias + (fl << 3));
            b1 = *(const float4*)(bias + (fl << 3) + 4);
        }
        float bv[8] = { b0.x, b0.y, b0.z, b0.w, b1.x, b1.y, b1.z, b1.w };
        float* row = &sT[nl * ST + (fl << 3)];
#pragma unroll
        for (int k = 0; k < 8; ++k) {
            float v = t[k] * di;
            if (MODE == 2) v = fmaxf(v + bv[k], 0.f);
            row[k] = v;
        }
    }
    __syncthreads();

    // matvec over the 32 staged rows: thread = 2 slots x 4 cols
    int rg = tid >> 4;                 // 0..15 -> slots 2rg, 2rg+1
    int cq = (tid & 15) << 2;          // col quad
    if (cq < M) {
        float s0[4] = {}, s1[4] = {};
#pragma unroll 8
        for (int k = 0; k < 64; ++k) {
            float4 w = *(const float4*)&sW[k * M + cq];
            float a0 = sT[(rg * 2) * ST + k];
            float a1 = sT[(rg * 2 + 1) * ST + k];
            s0[0] += a0 * w.x; s0[1] += a0 * w.y; s0[2] += a0 * w.z; s0[3] += a0 * w.w;
            s1[0] += a1 * w.x; s1[1] += a1 * w.y; s1[2] += a1 * w.z; s1[3] += a1 * w.w;
        }
#pragma unroll
        for (int r = 0; r < 2; ++r) {
            float* s = (r == 0) ? s0 : s1;
            int pos2 = n0 + rg * 2 + r;
            if (pos2 < n) {
                int node2 = order[pos2];
                if (MODE == 2) {
                    float d2 = dinv[node2];
                    union { uint2 u; __half2 h[2]; } P;
                    P.h[0] = __float22half2_rn(make_float2(s[0] * d2, s[1] * d2));
                    P.h[1] = __float22half2_rn(make_float2(s[2] * d2, s[3] * d2));
                    *(uint2*)((__half*)outv + ((size_t)node2 << 6) + cq) = P.u;
                } else {
                    float4 o = make_float4(s[0] + bias2[cq],     s[1] + bias2[cq + 1],
                                           s[2] + bias2[cq + 2], s[3] + bias2[cq + 3]);
                    *(float4*)((float*)outv + (size_t)node2 * 40 + cq) = o;
                }
            }
        }
    }
}

extern "C" void kernel_launch(void* const* d_in, const int* in_sizes, int n_in,
                              void* d_out, int out_size, void* d_ws, size_t ws_size,
                              hipStream_t stream) {
    const float* x  = (const float*)d_in[0];
    const int*   ei = (const int*)d_in[1];   // [2 x E]: row0 = src, row1 = dst
    const float* W1 = (const float*)d_in[2];
    const float* b1 = (const float*)d_in[3];
    const float* W2 = (const float*)d_in[4];
    const float* b2 = (const float*)d_in[5];
    const float* W3 = (const float*)d_in[6];
    const float* b3 = (const float*)d_in[7];
    float* out = (float*)d_out;

    const int* src = ei;
    const int* dst = ei + NE;

    // workspace: H[L1] | bsum[512] | rowptr[NPAD] | dinv[NPAD] | order[NPAD] |
    //            begend[NPAD] int2 | pairs[NE] | csr[NE] | gA | gB (half)
    unsigned* H      = (unsigned*)d_ws;
    unsigned* bsum   = H + L1;
    int*      rowptr = (int*)(bsum + 512);
    float*    dinv   = (float*)(rowptr + NPAD);
    int*      order  = (int*)(dinv + NPAD);
    int2*     begend = (int2*)(order + NPAD);
    unsigned* pairs  = (unsigned*)(begend + NPAD);
    int*      csr    = (int*)(pairs + NE);
    __half*   gA     = (__half*)(csr + NE);
    __half*   gB     = gA + (size_t)NN * 64;

    const int B = 256;
    const int gG = (NN + 31) / 32;
    const int gAgg = (NN + 31) / 32;      // 32 ranked slots per block
    const int nScan = (L1 + 255) / 256;   // 391

    // ---- CSR build (bucket sort + degree-rank order) ----
    k_hist<<<NB, B, 0, stream>>>(dst, H);
    k_scanA<<<nScan, B, 0, stream>>>(H, bsum, L1);
    k_scanB<<<1, 512, 0, stream>>>(bsum, nScan);
    k_scanC<<<nScan, B, 0, stream>>>(H, bsum, L1);
    k_scat<<<NB, B, 0, stream>>>(src, dst, H, pairs);
    k_bucket<<<D1, B, 0, stream>>>(H, pairs, rowptr, dinv, csr, order, begend);

    // ---- layer 1 GEMM (scaled fp16 out): gA = fp16(dinv .* (x @ W1)) ----
    k_gemm1<<<gG, B, 0, stream>>>(x, W1, dinv, gA, NN);
    // ---- AGG1 fused: gB = fp16(dinv .* (relu(dinv*t + b1) @ W2)) ----
    k_agg<2><<<gAgg, B, 0, stream>>>(order, begend, csr, gA, dinv, b1, W2, nullptr, gB, NN);
    // ---- AGG2: gA = fp16(dinv .* relu(dinv*t + b2)) ----
    k_agg<1><<<gAgg, B, 0, stream>>>(order, begend, csr, gB, dinv, b2, nullptr, nullptr, gA, NN);
    // ---- AGG3 fused: out = (dinv*t) @ W3 + b3 ----
    k_agg<3><<<gAgg, B, 0, stream>>>(order, begend, csr, gA, dinv, nullptr, W3, b3, out, NN);
}

// Round 12
// 184.390 us; speedup vs baseline: 1.1212x; 1.1212x over previous
//
#include <hip/hip_runtime.h>
#include <hip/hip_fp16.h>

#define NN 100000
#define NE 1600000
#define NPAD 100352          // NN rounded up to 256
#define ST 68                // LDS t-tile stride (16B-aligned rows, conflict-checked)
#define SXS 68               // gemm1 sX stride: 68%32=4 -> r0-groups hit distinct banks
#define NB 256               // hist/scatter blocks (NE % NB == 0 -> 6250 edges each)
#define CE (NE / NB)
#define D1 391               // dst>>8 buckets (99999>>8 = 390)
#define L1 (D1 * NB)         // flattened hist size = 100096

// ================= CSR build: bucket sort, ZERO scattered global atomics ======

__global__ __launch_bounds__(256) void k_hist(const int* __restrict__ dst,
                                              unsigned* __restrict__ H) {
    __shared__ unsigned h[D1];
    int b = blockIdx.x, t = threadIdx.x;
    for (int i = t; i < D1; i += 256) h[i] = 0;
    __syncthreads();
    int beg = b * CE, end = beg + CE;
    for (int i = beg + t; i < end; i += 256)
        atomicAdd(&h[((unsigned)dst[i]) >> 8], 1u);
    __syncthreads();
    for (int d = t; d < D1; d += 256) H[d * NB + b] = h[d];
}

__global__ __launch_bounds__(256) void k_scanA(const unsigned* __restrict__ in,
                                               unsigned* __restrict__ bsum, int L) {
    __shared__ unsigned sp[256];
    int i = blockIdx.x * 256 + threadIdx.x;
    sp[threadIdx.x] = (i < L) ? in[i] : 0;
    __syncthreads();
    for (int off = 128; off > 0; off >>= 1) {
        if (threadIdx.x < off) sp[threadIdx.x] += sp[threadIdx.x + off];
        __syncthreads();
    }
    if (threadIdx.x == 0) bsum[blockIdx.x] = sp[0];
}

__global__ __launch_bounds__(512) void k_scanB(unsigned* __restrict__ bsum, int nb) {
    __shared__ unsigned sp[512];
    int t = threadIdx.x;
    unsigned v = (t < nb) ? bsum[t] : 0;
    sp[t] = v;
    __syncthreads();
    for (int off = 1; off < 512; off <<= 1) {
        unsigned u = (t >= off) ? sp[t - off] : 0;
        __syncthreads();
        sp[t] += u;
        __syncthreads();
    }
    if (t < nb) bsum[t] = sp[t] - v;      // exclusive
}

__global__ __launch_bounds__(256) void k_scanC(unsigned* __restrict__ H,
                                               const unsigned* __restrict__ bsum, int L) {
    __shared__ unsigned sp[256];
    int t = threadIdx.x, i = blockIdx.x * 256 + t;
    unsigned v = (i < L) ? H[i] : 0;
    sp[t] = v;
    __syncthreads();
    for (int off = 1; off < 256; off <<= 1) {
        unsigned u = (t >= off) ? sp[t - off] : 0;
        __syncthreads();
        sp[t] += u;
        __syncthreads();
    }
    if (i < L) H[i] = bsum[blockIdx.x] + sp[t] - v;
}

__global__ __launch_bounds__(256) void k_scat(const int* __restrict__ src,
                                              const int* __restrict__ dst,
                                              const unsigned* __restrict__ H,
                                              unsigned* __restrict__ pairs) {
    __shared__ unsigned base[D1];
    __shared__ unsigned run[D1];
    int b = blockIdx.x, t = threadIdx.x;
    for (int d = t; d < D1; d += 256) { base[d] = H[d * NB + b]; run[d] = 0; }
    __syncthreads();
    int beg = b * CE, end = beg + CE;
    for (int i = beg + t; i < end; i += 256) {
        unsigned dv = (unsigned)dst[i];
        unsigned d = dv >> 8;
        unsigned r = atomicAdd(&run[d], 1u);
        pairs[base[d] + r] = ((dv & 255u) << 24) | (unsigned)src[i];
    }
}

__global__ __launch_bounds__(256) void k_bucket(const unsigned* __restrict__ H,
                                                const unsigned* __restrict__ pairs,
                                                int* __restrict__ rowptr,
                                                float* __restrict__ dinv,
                                                int* __restrict__ csr) {
    __shared__ unsigned h[256], sc[256], run[256];
    int b = blockIdx.x, t = threadIdx.x;
    unsigned S = H[b * NB];
    unsigned Send = (b + 1 < D1) ? H[(b + 1) * NB] : NE;
    h[t] = 0; run[t] = 0;
    __syncthreads();
    for (unsigned i = S + t; i < Send; i += 256)
        atomicAdd(&h[pairs[i] >> 24], 1u);
    __syncthreads();
    unsigned v = h[t];
    sc[t] = v;
    __syncthreads();
    for (int off = 1; off < 256; off <<= 1) {
        unsigned u = (t >= off) ? sc[t - off] : 0;
        __syncthreads();
        sc[t] += u;
        __syncthreads();
    }
    unsigned ex = sc[t] - v;               // exclusive
    int node = (b << 8) + t;
    if (node < NN) {
        rowptr[node] = (int)(S + ex);
        dinv[node] = rsqrtf((float)v + 1.0f);   // +1 = self-loop
    }
    if (b == 0 && t == 0) rowptr[NN] = NE;
    sc[t] = ex;
    __syncthreads();
    for (unsigned i = S + t; i < Send; i += 256) {
        unsigned p = pairs[i];
        unsigned k = p >> 24;
        unsigned r = atomicAdd(&run[k], 1u);
        csr[S + sc[k] + r] = (int)(p & 0xFFFFFFu);
    }
}

// ---------------- layer-1 GEMM: g1 = fp16( dinv .* (x @ W1) ) ----------------

__global__ __launch_bounds__(256, 4) void k_gemm1(const float* __restrict__ A,
                                                  const float* __restrict__ W,
                                                  const float* __restrict__ dinv,
                                                  __half* __restrict__ out, int n) {
    __shared__ float sX[32 * SXS];
    __shared__ float sW[64 * 64];
    int row0 = blockIdx.x * 32;
    for (int i = threadIdx.x; i < 16 * 64; i += 256)
        ((float4*)sW)[i] = ((const float4*)W)[i];
    for (int i = threadIdx.x; i < 32 * 16; i += 256) {
        int r = i >> 4, c4 = i & 15;
        int row = row0 + r;
        float4 v = (row < n) ? ((const float4*)(A + ((size_t)row << 6)))[c4]
                             : make_float4(0.f, 0.f, 0.f, 0.f);
        *(float4*)&sX[r * SXS + (c4 << 2)] = v;
    }
    __syncthreads();

    int ci = (threadIdx.x & 15) * 4;
    int r0 = (threadIdx.x >> 4) * 2;
    float acc[2][4] = {};
#pragma unroll 16
    for (int k = 0; k < 64; ++k) {
        float a0 = sX[r0 * SXS + k];
        float a1 = sX[(r0 + 1) * SXS + k];
        float4 w = *(const float4*)&sW[(k << 6) + ci];
        acc[0][0] += a0 * w.x; acc[0][1] += a0 * w.y;
        acc[0][2] += a0 * w.z; acc[0][3] += a0 * w.w;
        acc[1][0] += a1 * w.x; acc[1][1] += a1 * w.y;
        acc[1][2] += a1 * w.z; acc[1][3] += a1 * w.w;
    }
#pragma unroll
    for (int rr = 0; rr < 2; ++rr) {
        int row = row0 + r0 + rr;
        if (row < n) {
            float di = dinv[row];
            union { uint2 u; __half2 h[2]; } P;
            P.h[0] = __float22half2_rn(make_float2(acc[rr][0] * di, acc[rr][1] * di));
            P.h[1] = __float22half2_rn(make_float2(acc[rr][2] * di, acc[rr][3] * di));
            *(uint2*)(out + ((size_t)row << 6) + ci) = P.u;
        }
    }
}

// ---------------- aggregate over 64-dim g-rows + fused matvec (R10 structure) ----
// t[d] = sum_{s in N(d)} g[s] + g[d]       (g = dinv .* h, 64-dim fp16 rows)
// out = fp16( dinv .* (relu(dinv*t + bias) @ Wn) )   [M cols, fp16 packed]

#define ACC8(r) { \
    const __half2* hh_ = (const __half2*)&(r); \
    float2 f_; \
    f_ = __half22float2(hh_[0]); a[0].x += f_.x; a[0].y += f_.y; \
    f_ = __half22float2(hh_[1]); a[1].x += f_.x; a[1].y += f_.y; \
    f_ = __half22float2(hh_[2]); a[2].x += f_.x; a[2].y += f_.y; \
    f_ = __half22float2(hh_[3]); a[3].x += f_.x; a[3].y += f_.y; }

template <int M>
__global__ __launch_bounds__(256) void k_agg64(const int* __restrict__ rowptr,
                                               const int* __restrict__ csr,
                                               const __half* __restrict__ g,
                                               const float* __restrict__ dinv,
                                               const float* __restrict__ bias,
                                               const float* __restrict__ Wn,
                                               __half* __restrict__ outh, int n) {
    __shared__ float sW[64 * M];
    __shared__ float sT[32 * ST];
    int tid = threadIdx.x;
    for (int i = tid; i < 16 * M; i += 256)
        ((float4*)sW)[i] = ((const float4*)Wn)[i];
    int n0 = blockIdx.x << 5;
    int lane = tid & 63, wid = tid >> 6;
    int ng = lane >> 3, fl = lane & 7;
    int nl = (wid << 3) + ng;              // block-local node 0..31
    int node = n0 + nl;
    bool valid = node < n;
    const uint4* g4 = (const uint4*)g;     // one row = 8 uint4 (64 halves)

    int beg = 0, end = 0;
    if (valid) { beg = rowptr[node]; end = rowptr[node + 1]; }
    float2 a[4] = {};
    int j = beg;
    for (; j + 4 <= end; j += 4) {         // 4 independent gathers in flight
        int s0 = csr[j], s1 = csr[j + 1], s2 = csr[j + 2], s3 = csr[j + 3];
        uint4 r0 = g4[((size_t)s0 << 3) + fl];
        uint4 r1 = g4[((size_t)s1 << 3) + fl];
        uint4 r2 = g4[((size_t)s2 << 3) + fl];
        uint4 r3 = g4[((size_t)s3 << 3) + fl];
        ACC8(r0); ACC8(r1); ACC8(r2); ACC8(r3);
    }
    for (; j < end; ++j) {
        int s = csr[j];
        uint4 r = g4[((size_t)s << 3) + fl];
        ACC8(r);
    }
    if (valid) {                           // self-loop
        uint4 r = g4[((size_t)node << 3) + fl];
        ACC8(r);
    }
    float di = valid ? dinv[node] : 0.f;
    float t[8] = { a[0].x, a[0].y, a[1].x, a[1].y, a[2].x, a[2].y, a[3].x, a[3].y };

    // stash h-row slice: h = relu(dinv*t + bias)
    {
        float4 b0 = *(const float4*)(bias + (fl << 3));
        float4 b1 = *(const float4*)(bias + (fl << 3) + 4);
        float bv[8] = { b0.x, b0.y, b0.z, b0.w, b1.x, b1.y, b1.z, b1.w };
        float* row = &sT[nl * ST + (fl << 3)];
#pragma unroll
        for (int k = 0; k < 8; ++k)
            row[k] = fmaxf(t[k] * di + bv[k], 0.f);
    }
    __syncthreads();

    // matvec over the 32 staged rows: thread = 2 slots x 4 cols
    int rg = tid >> 4;                 // 0..15 -> slots 2rg, 2rg+1
    int cq = (tid & 15) << 2;          // col quad
    if (cq < M) {
        float s0[4] = {}, s1[4] = {};
#pragma unroll 8
        for (int k = 0; k < 64; ++k) {
            float4 w = *(const float4*)&sW[k * M + cq];
            float a0 = sT[(rg * 2) * ST + k];
            float a1 = sT[(rg * 2 + 1) * ST + k];
            s0[0] += a0 * w.x; s0[1] += a0 * w.y; s0[2] += a0 * w.z; s0[3] += a0 * w.w;
            s1[0] += a1 * w.x; s1[1] += a1 * w.y; s1[2] += a1 * w.z; s1[3] += a1 * w.w;
        }
#pragma unroll
        for (int r = 0; r < 2; ++r) {
            float* s = (r == 0) ? s0 : s1;
            int node2 = n0 + rg * 2 + r;
            if (node2 < n) {
                float d2 = dinv[node2];
                union { uint2 u; __half2 h[2]; } P;
                P.h[0] = __float22half2_rn(make_float2(s[0] * d2, s[1] * d2));
                P.h[1] = __float22half2_rn(make_float2(s[2] * d2, s[3] * d2));
                *(uint2*)(outh + (size_t)node2 * M + cq) = P.u;
            }
        }
    }
}

// ---------------- final aggregate over 40-dim q-rows (80 B/edge) ----------------
// q = dinv .* (h2 @ W3)  (fp16, N x 40).  out[d] = dinv[d] * (sum q[s] + q[d]) + b3.
// 8-lane groups; lanes fl<5 each own a half8 slice (5*8 = 40).

__global__ __launch_bounds__(256) void k_agg40(const int* __restrict__ rowptr,
                                               const int* __restrict__ csr,
                                               const __half* __restrict__ q,
                                               const float* __restrict__ dinv,
                                               const float* __restrict__ bias,
                                               float* __restrict__ out, int n) {
    int tid = threadIdx.x;
    int n0 = blockIdx.x << 5;
    int lane = tid & 63, wid = tid >> 6;
    int ng = lane >> 3, fl = lane & 7;
    int nl = (wid << 3) + ng;
    int node = n0 + nl;
    bool valid = (node < n) && (fl < 5);

    int beg = 0, end = 0;
    if (valid) { beg = rowptr[node]; end = rowptr[node + 1]; }
    float2 a[4] = {};
    int j = beg;
    for (; j + 4 <= end; j += 4) {
        int s0 = csr[j], s1 = csr[j + 1], s2 = csr[j + 2], s3 = csr[j + 3];
        uint4 r0 = *(const uint4*)(q + (size_t)s0 * 40 + (fl << 3));
        uint4 r1 = *(const uint4*)(q + (size_t)s1 * 40 + (fl << 3));
        uint4 r2 = *(const uint4*)(q + (size_t)s2 * 40 + (fl << 3));
        uint4 r3 = *(const uint4*)(q + (size_t)s3 * 40 + (fl << 3));
        ACC8(r0); ACC8(r1); ACC8(r2); ACC8(r3);
    }
    for (; j < end; ++j) {
        int s = csr[j];
        uint4 r = *(const uint4*)(q + (size_t)s * 40 + (fl << 3));
        ACC8(r);
    }
    if (valid) {
        uint4 r = *(const uint4*)(q + (size_t)node * 40 + (fl << 3));  // self
        ACC8(r);
        float di = dinv[node];
        float t[8] = { a[0].x, a[0].y, a[1].x, a[1].y, a[2].x, a[2].y, a[3].x, a[3].y };
        float4 b0 = *(const float4*)(bias + (fl << 3));
        float4 b1 = *(const float4*)(bias + (fl << 3) + 4);
        float4 o0 = make_float4(t[0] * di + b0.x, t[1] * di + b0.y,
                                t[2] * di + b0.z, t[3] * di + b0.w);
        float4 o1 = make_float4(t[4] * di + b1.x, t[5] * di + b1.y,
                                t[6] * di + b1.z, t[7] * di + b1.w);
        float* op = out + (size_t)node * 40 + (fl << 3);
        *(float4*)op = o0;
        *(float4*)(op + 4) = o1;
    }
}

extern "C" void kernel_launch(void* const* d_in, const int* in_sizes, int n_in,
                              void* d_out, int out_size, void* d_ws, size_t ws_size,
                              hipStream_t stream) {
    const float* x  = (const float*)d_in[0];
    const int*   ei = (const int*)d_in[1];   // [2 x E]: row0 = src, row1 = dst
    const float* W1 = (const float*)d_in[2];
    const float* b1 = (const float*)d_in[3];
    const float* W2 = (const float*)d_in[4];
    const float* b2 = (const float*)d_in[5];
    const float* W3 = (const float*)d_in[6];
    const float* b3 = (const float*)d_in[7];
    float* out = (float*)d_out;

    const int* src = ei;
    const int* dst = ei + NE;

    // workspace: H[L1] | bsum[512] | rowptr[NPAD] | dinv[NPAD] | pairs[NE] |
    //            csr[NE] | gA half[N*64] | gB half[N*64] | gC half[N*40]
    unsigned* H      = (unsigned*)d_ws;
    unsigned* bsum   = H + L1;
    int*      rowptr = (int*)(bsum + 512);
    float*    dinv   = (float*)(rowptr + NPAD);
    unsigned* pairs  = (unsigned*)(dinv + NPAD);
    int*      csr    = (int*)(pairs + NE);
    __half*   gA     = (__half*)(csr + NE);
    __half*   gB     = gA + (size_t)NN * 64;
    __half*   gC     = gB + (size_t)NN * 64;

    const int B = 256;
    const int gG = (NN + 31) / 32;
    const int gAgg = (NN + 31) / 32;      // 32 nodes per block
    const int nScan = (L1 + 255) / 256;   // 391

    // ---- CSR build (bucket sort, no scattered global atomics) ----
    k_hist<<<NB, B, 0, stream>>>(dst, H);
    k_scanA<<<nScan, B, 0, stream>>>(H, bsum, L1);
    k_scanB<<<1, 512, 0, stream>>>(bsum, nScan);
    k_scanC<<<nScan, B, 0, stream>>>(H, bsum, L1);
    k_scat<<<NB, B, 0, stream>>>(src, dst, H, pairs);
    k_bucket<<<D1, B, 0, stream>>>(H, pairs, rowptr, dinv, csr);

    // ---- layer 1 GEMM (scaled fp16 out): gA = fp16(dinv .* (x @ W1)) ----
    k_gemm1<<<gG, B, 0, stream>>>(x, W1, dinv, gA, NN);
    // ---- AGG1 fused W2: gB = fp16(dinv .* (relu(dinv*t + b1) @ W2))  [N x 64] ----
    k_agg64<64><<<gAgg, B, 0, stream>>>(rowptr, csr, gA, dinv, b1, W2, gB, NN);
    // ---- AGG2 fused W3: gC = fp16(dinv .* (relu(dinv*t + b2) @ W3))  [N x 40] ----
    k_agg64<40><<<gAgg, B, 0, stream>>>(rowptr, csr, gB, dinv, b2, W3, gC, NN);
    // ---- AGG3 (40-dim gather): out = dinv*t3 + b3 ----
    k_agg40<<<gAgg, B, 0, stream>>>(rowptr, csr, gC, dinv, b3, out, NN);
}